// Round 14
// baseline (169.507 us; speedup 1.0000x reference)
//
#include <hip/hip_runtime.h>
#include <hip/hip_bf16.h>

#define Bb 512
#define Tt 512
#define Kk 64
#define START_TAG 62
#define STOP_TAG 63
#define LN2F 0.69314718055994530942f
#define LOG2E 1.44269504088896340736f

typedef __attribute__((ext_vector_type(8))) short bf16x8;  // 8 bf16 in 4 VGPRs
typedef __attribute__((ext_vector_type(4))) float f32x4;   // MFMA C/D

__device__ inline short f2bf(float x) {
    __hip_bfloat16 h = __float2bfloat16(x);
    short s; __builtin_memcpy(&s, &h, 2); return s;
}
__device__ inline unsigned cvtpk(float lo, float hi) {
    unsigned r;
    asm("v_cvt_pk_bf16_f32 %0, %1, %2" : "=v"(r) : "v"(lo), "v"(hi));
    return r;
}

// TWO sequences per 64-lane wave, alpha recursions interleaved.
// Engine per sequence = r8's bit-verified structure (absmax 0.0): exp-space
// MFMA matvec, tau k-mapping on A and B, D->B register identity, static
// 2-bank LDS F-path, one wave_barrier per iteration, r7 rescale ledger.
// Rationale (r13 post-mortem): r8 is ~70% latency bubble on ONE dependent
// chain; a second INDEPENDENT chain fills it. B columns stay replicated, so
// the unverified B-column lane mapping (root-cause suspect for r12/r13's
// matrix-path failures) is never exercised.
// Hot loop: both seqs to tc = min(len0,len1)&~1, no guards. Cold: r8 loops
// finish the longer sequence.
__global__ __launch_bounds__(64, 1) void crf_forward_dual(
    const float* __restrict__ feats,        // (B,T,K)
    const float* __restrict__ transitions,  // (K,K), trans[i,j] = score j->i
    const int* __restrict__ lengths,        // (B,)
    float* __restrict__ fwd_out)            // (B,)
{
    const int b0  = blockIdx.x * 2;
    const int l   = threadIdx.x;
    const int row = l & 15;
    const int g   = l >> 4;

    // F banks: [seq][parity][lane], natural layout (lane = tag)
    __shared__ __align__(16) float frl[2][2][Kk];

    // A fragments (shared by both seqs): slot r = exp(trans[16i+row][tau(c,r)])
    bf16x8 A00, A01, A10, A11, A20, A21, A30, A31, S0, S1;
#define MKA(Av, i, c) {                                                       \
    const float* p = transitions + (16*(i)+row)*Kk + 32*(c) + 4*g;            \
    float4 lo = *(const float4*)p; float4 hi = *(const float4*)(p + 16);      \
    Av[0]=f2bf(__expf(lo.x)); Av[1]=f2bf(__expf(lo.y));                       \
    Av[2]=f2bf(__expf(lo.z)); Av[3]=f2bf(__expf(lo.w));                       \
    Av[4]=f2bf(__expf(hi.x)); Av[5]=f2bf(__expf(hi.y));                       \
    Av[6]=f2bf(__expf(hi.z)); Av[7]=f2bf(__expf(hi.w)); }
    MKA(A00,0,0) MKA(A01,0,1) MKA(A10,1,0) MKA(A11,1,1)
    MKA(A20,2,0) MKA(A21,2,1) MKA(A30,3,0) MKA(A31,3,1)
#undef MKA
#define MKS(Av, c) {                                                          \
    const float* p = transitions + STOP_TAG*Kk + 32*(c) + 4*g;                \
    float4 lo = *(const float4*)p; float4 hi = *(const float4*)(p + 16);      \
    const bool z = (row == 0);                                                \
    Av[0]=z?f2bf(__expf(lo.x)):(short)0; Av[1]=z?f2bf(__expf(lo.y)):(short)0; \
    Av[2]=z?f2bf(__expf(lo.z)):(short)0; Av[3]=z?f2bf(__expf(lo.w)):(short)0; \
    Av[4]=z?f2bf(__expf(hi.x)):(short)0; Av[5]=z?f2bf(__expf(hi.y)):(short)0; \
    Av[6]=z?f2bf(__expf(hi.z)):(short)0; Av[7]=z?f2bf(__expf(hi.w)):(short)0; }
    MKS(S0,0) MKS(S1,1)
#undef MKS

    const int len0 = lengths[b0];
    const int len1 = lengths[b0 + 1];
    const float* fb0 = feats + (size_t)b0 * Tt * Kk + l;
    const float* fb1 = fb0 + (size_t)Tt * Kk;

    bf16x8 B0_0 = {}, B1_0 = {}, B0_1 = {}, B1_1 = {};
    if (g == 3) { B1_0[6] = (short)0x3F80; B1_1[6] = (short)0x3F80; }

    const float* bk00 = &frl[0][0][4 * g];
    const float* bk01 = &frl[0][1][4 * g];
    const float* bk10 = &frl[1][0][4 * g];
    const float* bk11 = &frl[1][1][4 * g];

    // ---- prologue (both seqs) ----
    const float p00 = __builtin_amdgcn_exp2f(fb0[0]      * LOG2E);
    const float p01 = __builtin_amdgcn_exp2f(fb0[Kk]     * LOG2E);
    const float p02 = __builtin_amdgcn_exp2f(fb0[2 * Kk] * LOG2E);
    const float p03 = __builtin_amdgcn_exp2f(fb0[3 * Kk] * LOG2E);
    const float p10 = __builtin_amdgcn_exp2f(fb1[0]      * LOG2E);
    const float p11 = __builtin_amdgcn_exp2f(fb1[Kk]     * LOG2E);
    const float p12 = __builtin_amdgcn_exp2f(fb1[2 * Kk] * LOG2E);
    const float p13 = __builtin_amdgcn_exp2f(fb1[3 * Kk] * LOG2E);
    frl[0][0][l] = p00; frl[0][1][l] = p01;
    frl[1][0][l] = p10; frl[1][1][l] = p11;
    __builtin_amdgcn_wave_barrier();
    f32x4 FA0_0, FA1_0, FA2_0, FA3_0, FB0_0, FB1_0, FB2_0, FB3_0;
    f32x4 FA0_1, FA1_1, FA2_1, FA3_1, FB0_1, FB1_1, FB2_1, FB3_1;
    FA0_0 = *(const f32x4*)(bk00);      FA1_0 = *(const f32x4*)(bk00 + 16);
    FA2_0 = *(const f32x4*)(bk00 + 32); FA3_0 = *(const f32x4*)(bk00 + 48);
    FB0_0 = *(const f32x4*)(bk01);      FB1_0 = *(const f32x4*)(bk01 + 16);
    FB2_0 = *(const f32x4*)(bk01 + 32); FB3_0 = *(const f32x4*)(bk01 + 48);
    FA0_1 = *(const f32x4*)(bk10);      FA1_1 = *(const f32x4*)(bk10 + 16);
    FA2_1 = *(const f32x4*)(bk10 + 32); FA3_1 = *(const f32x4*)(bk10 + 48);
    FB0_1 = *(const f32x4*)(bk11);      FB1_1 = *(const f32x4*)(bk11 + 16);
    FB2_1 = *(const f32x4*)(bk11 + 32); FB3_1 = *(const f32x4*)(bk11 + 48);
    __builtin_amdgcn_wave_barrier();
    frl[0][0][l] = p02; frl[0][1][l] = p03;   // fr(2), fr(3) per seq
    frl[1][0][l] = p12; frl[1][1][l] = p13;

    // emit rings, 4 deep: rows t+4..t+7
    float e0_0 = fb0[4*Kk], e1_0 = fb0[5*Kk], e2_0 = fb0[6*Kk], e3_0 = fb0[7*Kk];
    float e0_1 = fb1[4*Kk], e1_1 = fb1[5*Kk], e2_1 = fb1[6*Kk], e3_1 = fb1[7*Kk];

    const f32x4 zz = {0.f, 0.f, 0.f, 0.f};
    int ktot0 = 0, kq00 = 0, kq10 = 0, kemb0 = 0;
    int ktot1 = 0, kq01 = 0, kq11 = 0, kemb1 = 0;
    float pA0, pB0, pA1, pB1;

#define MFMA16(Aa, Bx, Cc) __builtin_amdgcn_mfma_f32_16x16x32_bf16(Aa, Bx, Cc, 0, 0, 0)

#define STEP(B0v, B1v, F0_, F1_, F2_, F3_, PR) {                              \
    f32x4 d0 = MFMA16(A00, B0v, zz); d0 = MFMA16(A01, B1v, d0);               \
    f32x4 d1 = MFMA16(A10, B0v, zz); d1 = MFMA16(A11, B1v, d1);               \
    f32x4 d2 = MFMA16(A20, B0v, zz); d2 = MFMA16(A21, B1v, d2);               \
    f32x4 d3 = MFMA16(A30, B0v, zz); d3 = MFMA16(A31, B1v, d3);               \
    f32x4 m0 = d0 * F0_, m1 = d1 * F1_, m2 = d2 * F2_, m3 = d3 * F3_;         \
    PR = m0[0];                                                               \
    union { unsigned u[4]; bf16x8 v; } nb0, nb1;                              \
    nb0.u[0] = cvtpk(m0[0], m0[1]); nb0.u[1] = cvtpk(m0[2], m0[3]);           \
    nb0.u[2] = cvtpk(m1[0], m1[1]); nb0.u[3] = cvtpk(m1[2], m1[3]);           \
    nb1.u[0] = cvtpk(m2[0], m2[1]); nb1.u[1] = cvtpk(m2[2], m2[3]);           \
    nb1.u[2] = cvtpk(m3[0], m3[1]); nb1.u[3] = cvtpk(m3[2], m3[3]);           \
    B0v = nb0.v; B1v = nb1.v; }

    // ---- HOT loop: both sequences, no guards ----
    const int mn = (len0 < len1) ? len0 : len1;
    const int tc = mn & ~1;
    int t = 0;
    for (; t < tc; t += 2) {
        f32x4 NA0_0 = *(const f32x4*)(bk00);      f32x4 NA1_0 = *(const f32x4*)(bk00 + 16);
        f32x4 NA2_0 = *(const f32x4*)(bk00 + 32); f32x4 NA3_0 = *(const f32x4*)(bk00 + 48);
        f32x4 NB0_0 = *(const f32x4*)(bk01);      f32x4 NB1_0 = *(const f32x4*)(bk01 + 16);
        f32x4 NB2_0 = *(const f32x4*)(bk01 + 32); f32x4 NB3_0 = *(const f32x4*)(bk01 + 48);
        f32x4 NA0_1 = *(const f32x4*)(bk10);      f32x4 NA1_1 = *(const f32x4*)(bk10 + 16);
        f32x4 NA2_1 = *(const f32x4*)(bk10 + 32); f32x4 NA3_1 = *(const f32x4*)(bk10 + 48);
        f32x4 NB0_1 = *(const f32x4*)(bk11);      f32x4 NB1_1 = *(const f32x4*)(bk11 + 16);
        f32x4 NB2_1 = *(const f32x4*)(bk11 + 32); f32x4 NB3_1 = *(const f32x4*)(bk11 + 48);
        const float frA_0 = __builtin_amdgcn_exp2f(fmaf(e0_0, LOG2E, -(float)kemb0));
        const float frB_0 = __builtin_amdgcn_exp2f(e1_0 * LOG2E);
        const float frA_1 = __builtin_amdgcn_exp2f(fmaf(e0_1, LOG2E, -(float)kemb1));
        const float frB_1 = __builtin_amdgcn_exp2f(e1_1 * LOG2E);

        // interleaved: two independent chains fill each other's stalls
        STEP(B0_0, B1_0, FA0_0, FA1_0, FA2_0, FA3_0, pA0)
        STEP(B0_1, B1_1, FA0_1, FA1_1, FA2_1, FA3_1, pA1)
        STEP(B0_0, B1_0, FB0_0, FB1_0, FB2_0, FB3_0, pB0)
        STEP(B0_1, B1_1, FB0_1, FB1_1, FB2_1, FB3_1, pB1)

        __builtin_amdgcn_wave_barrier();   // all DS reads above precede writes
        frl[0][0][l] = frA_0; frl[0][1][l] = frB_0;
        frl[1][0][l] = frA_1; frl[1][1][l] = frB_1;

        // ledgers (r7-validated in-flight accounting), per seq
        ktot0 += kq00;
        ktot1 += kq01;
        const unsigned pb0 =
            (unsigned)__builtin_amdgcn_readfirstlane(__float_as_int(pB0));
        const unsigned pb1 =
            (unsigned)__builtin_amdgcn_readfirstlane(__float_as_int(pB1));
        int kn0 = ((int)((pb0 >> 23) & 255) - 127) - kq10 - kemb0;
        int kn1 = ((int)((pb1 >> 23) & 255) - 127) - kq11 - kemb1;
        kn0 = (kn0 > 100) ? 100 : ((kn0 < -100) ? -100 : kn0);
        kn1 = (kn1 > 100) ? 100 : ((kn1 < -100) ? -100 : kn1);
        kq00 = kq10; kq10 = kemb0; kemb0 = kn0;
        kq01 = kq11; kq11 = kemb1; kemb1 = kn1;
        FA0_0 = NA0_0; FA1_0 = NA1_0; FA2_0 = NA2_0; FA3_0 = NA3_0;
        FB0_0 = NB0_0; FB1_0 = NB1_0; FB2_0 = NB2_0; FB3_0 = NB3_0;
        FA0_1 = NA0_1; FA1_1 = NA1_1; FA2_1 = NA2_1; FA3_1 = NA3_1;
        FB0_1 = NB0_1; FB1_1 = NB1_1; FB2_1 = NB2_1; FB3_1 = NB3_1;
        e0_0 = e2_0; e1_0 = e3_0; e0_1 = e2_1; e1_1 = e3_1;
        const int r0 = (t + 8 < Tt) ? t + 8 : Tt - 1;
        const int r1 = (t + 9 < Tt) ? t + 9 : Tt - 1;
        e2_0 = fb0[r0 * Kk]; e3_0 = fb0[r1 * Kk];
        e2_1 = fb1[r0 * Kk]; e3_1 = fb1[r1 * Kk];
        (void)pA0; (void)pA1;
    }

    // ---- COLD: finish seq 0 (r8 loop; 0 iterations if done) ----
    int t0 = t;
    for (; t0 + 1 < len0; t0 += 2) {
        f32x4 NA0 = *(const f32x4*)(bk00);      f32x4 NA1 = *(const f32x4*)(bk00 + 16);
        f32x4 NA2 = *(const f32x4*)(bk00 + 32); f32x4 NA3 = *(const f32x4*)(bk00 + 48);
        f32x4 NB0 = *(const f32x4*)(bk01);      f32x4 NB1 = *(const f32x4*)(bk01 + 16);
        f32x4 NB2 = *(const f32x4*)(bk01 + 32); f32x4 NB3 = *(const f32x4*)(bk01 + 48);
        const float frA = __builtin_amdgcn_exp2f(fmaf(e0_0, LOG2E, -(float)kemb0));
        const float frB = __builtin_amdgcn_exp2f(e1_0 * LOG2E);
        STEP(B0_0, B1_0, FA0_0, FA1_0, FA2_0, FA3_0, pA0)
        STEP(B0_0, B1_0, FB0_0, FB1_0, FB2_0, FB3_0, pB0)
        __builtin_amdgcn_wave_barrier();
        frl[0][0][l] = frA; frl[0][1][l] = frB;
        ktot0 += kq00;
        const unsigned pb =
            (unsigned)__builtin_amdgcn_readfirstlane(__float_as_int(pB0));
        int kn = ((int)((pb >> 23) & 255) - 127) - kq10 - kemb0;
        kn = (kn > 100) ? 100 : ((kn < -100) ? -100 : kn);
        kq00 = kq10; kq10 = kemb0; kemb0 = kn;
        FA0_0 = NA0; FA1_0 = NA1; FA2_0 = NA2; FA3_0 = NA3;
        FB0_0 = NB0; FB1_0 = NB1; FB2_0 = NB2; FB3_0 = NB3;
        e0_0 = e2_0; e1_0 = e3_0;
        const int r0 = (t0 + 8 < Tt) ? t0 + 8 : Tt - 1;
        const int r1 = (t0 + 9 < Tt) ? t0 + 9 : Tt - 1;
        e2_0 = fb0[r0 * Kk]; e3_0 = fb0[r1 * Kk];
        (void)pA0;
    }
    if (t0 < len0) {
        STEP(B0_0, B1_0, FA0_0, FA1_0, FA2_0, FA3_0, pA0)
        ktot0 += kq00;
        (void)pA0;
    }

    // ---- COLD: finish seq 1 ----
    int t1 = t;
    for (; t1 + 1 < len1; t1 += 2) {
        f32x4 NA0 = *(const f32x4*)(bk10);      f32x4 NA1 = *(const f32x4*)(bk10 + 16);
        f32x4 NA2 = *(const f32x4*)(bk10 + 32); f32x4 NA3 = *(const f32x4*)(bk10 + 48);
        f32x4 NB0 = *(const f32x4*)(bk11);      f32x4 NB1 = *(const f32x4*)(bk11 + 16);
        f32x4 NB2 = *(const f32x4*)(bk11 + 32); f32x4 NB3 = *(const f32x4*)(bk11 + 48);
        const float frA = __builtin_amdgcn_exp2f(fmaf(e0_1, LOG2E, -(float)kemb1));
        const float frB = __builtin_amdgcn_exp2f(e1_1 * LOG2E);
        STEP(B0_1, B1_1, FA0_1, FA1_1, FA2_1, FA3_1, pA1)
        STEP(B0_1, B1_1, FB0_1, FB1_1, FB2_1, FB3_1, pB1)
        __builtin_amdgcn_wave_barrier();
        frl[1][0][l] = frA; frl[1][1][l] = frB;
        ktot1 += kq01;
        const unsigned pb =
            (unsigned)__builtin_amdgcn_readfirstlane(__float_as_int(pB1));
        int kn = ((int)((pb >> 23) & 255) - 127) - kq11 - kemb1;
        kn = (kn > 100) ? 100 : ((kn < -100) ? -100 : kn);
        kq01 = kq11; kq11 = kemb1; kemb1 = kn;
        FA0_1 = NA0; FA1_1 = NA1; FA2_1 = NA2; FA3_1 = NA3;
        FB0_1 = NB0; FB1_1 = NB1; FB2_1 = NB2; FB3_1 = NB3;
        e0_1 = e2_1; e1_1 = e3_1;
        const int r0 = (t1 + 8 < Tt) ? t1 + 8 : Tt - 1;
        const int r1 = (t1 + 9 < Tt) ? t1 + 9 : Tt - 1;
        e2_1 = fb1[r0 * Kk]; e3_1 = fb1[r1 * Kk];
        (void)pA1;
    }
    if (t1 < len1) {
        STEP(B0_1, B1_1, FA0_1, FA1_1, FA2_1, FA3_1, pA1)
        ktot1 += kq01;
        (void)pA1;
    }

    // ---- terminals ----
    f32x4 d4 = MFMA16(S0, B0_0, zz); d4 = MFMA16(S1, B1_0, d4);
    f32x4 d5 = MFMA16(S0, B0_1, zz); d5 = MFMA16(S1, B1_1, d5);
    const float tm0 = __uint_as_float(
        (unsigned)__builtin_amdgcn_readfirstlane(__float_as_int(d4[0])));
    const float tm1 = __uint_as_float(
        (unsigned)__builtin_amdgcn_readfirstlane(__float_as_int(d5[0])));
    if (l == 0) {
        fwd_out[b0]     = (float)ktot0 * LN2F + logf(tm0);
        fwd_out[b0 + 1] = (float)ktot1 * LN2F + logf(tm1);
    }
#undef STEP
#undef MFMA16
}

// Gold path score: fully parallel over t (lane-strided).
__global__ __launch_bounds__(64) void crf_gold_kernel(
    const float* __restrict__ feats,
    const float* __restrict__ transitions,
    const int* __restrict__ tags,
    const int* __restrict__ lengths,
    float* __restrict__ gold_out)
{
    const int b = blockIdx.x;
    const int lane = threadIdx.x;
    const int len = lengths[b];
    const int* tb = tags + b * Tt;
    const float* fb = feats + (size_t)b * Tt * Kk;

    float acc = 0.f;
    for (int t = lane; t < len; t += 64) {
        const int tg = tb[t];
        const int prev = (t == 0) ? START_TAG : tb[t - 1];
        acc += transitions[tg * Kk + prev];
        acc += fb[t * Kk + tg];
    }
    if (lane == 0) acc += transitions[STOP_TAG * Kk + tb[len - 1]];
#pragma unroll
    for (int off = 32; off >= 1; off >>= 1) acc += __shfl_xor(acc, off, 64);
    if (lane == 0) gold_out[b] = acc;
}

__global__ __launch_bounds__(512) void crf_reduce_kernel(
    const float* __restrict__ fwd, const float* __restrict__ gold,
    float* __restrict__ out)
{
    const int i = threadIdx.x;
    float v = fwd[i] - gold[i];
#pragma unroll
    for (int off = 32; off >= 1; off >>= 1) v += __shfl_xor(v, off, 64);
    __shared__ float ws[8];
    if ((i & 63) == 0) ws[i >> 6] = v;
    __syncthreads();
    if (i < 8) {
        float s = ws[i];
#pragma unroll
        for (int off = 4; off >= 1; off >>= 1) s += __shfl_xor(s, off, 8);
        if (i == 0) out[0] = s * (1.0f / (float)Bb);
    }
}

extern "C" void kernel_launch(void* const* d_in, const int* in_sizes, int n_in,
                              void* d_out, int out_size, void* d_ws, size_t ws_size,
                              hipStream_t stream) {
    const float* feats = (const float*)d_in[0];
    const float* trans = (const float*)d_in[1];
    const int* tags = (const int*)d_in[2];
    const int* lengths = (const int*)d_in[3];
    float* out = (float*)d_out;
    float* fwd = (float*)d_ws;          // ~4 KB d_ws use (proven safe)
    float* gold = fwd + Bb;

    crf_gold_kernel<<<Bb, 64, 0, stream>>>(feats, trans, tags, lengths, gold);
    crf_forward_dual<<<Bb / 2, 64, 0, stream>>>(feats, trans, lengths, fwd);
    crf_reduce_kernel<<<1, 512, 0, stream>>>(fwd, gold, out);
}

// Round 15
// 96.220 us; speedup vs baseline: 1.7617x; 1.7617x over previous
//
#include <hip/hip_runtime.h>
#include <hip/hip_bf16.h>

#define Bb 512
#define Tt 512
#define Kk 64
#define START_TAG 62
#define STOP_TAG 63
#define LN2F 0.69314718055994530942f
#define LOG2E 1.44269504088896340736f

typedef __attribute__((ext_vector_type(8))) short bf16x8;  // 8 bf16 in 4 VGPRs
typedef __attribute__((ext_vector_type(4))) float f32x4;   // MFMA C/D

__device__ inline short f2bf(float x) {
    __hip_bfloat16 h = __float2bfloat16(x);
    short s; __builtin_memcpy(&s, &h, 2); return s;
}
// pack 2 f32 -> 2 bf16 in one instruction
__device__ inline unsigned cvtpk(float lo, float hi) {
    unsigned r;
    asm("v_cvt_pk_bf16_f32 %0, %1, %2" : "=v"(r) : "v"(lo), "v"(hi));
    return r;
}

// FINAL (= round-8 kernel, best measured: 97.1 us, absmax 0.0).
// One sequence per 64-lane wave; alpha recursion as MFMA matvec in exp-space.
// Layout (HW-verified r4-r14): tag tau(c,r)=32c+16*(r>=4)+4g+(r&3) on both A
// and B sides; D tile i reg r = tag 16i+4g+r -> D feeds next B with register
// moves only. Static 2-bank LDS F-path, one wave_barrier per iteration,
// r7-validated in-flight rescale ledger (exact ktot accounting).
//
// Why this is the floor of the verified design space (session evidence):
//  - r5 vs r7: prefetch depth 4 vs 8 -> null (not vmcnt latency)
//  - r8: barriers 4 -> 1 -> null (not fence-forfeited overlap)
//  - r9: unchained MFMAs -> REGRESSED (not SrcC dependency latency)
//  - r10: 4-bank rotating LDS -> regressed; pkmul neutral
//  - r11: bpermute F-path -> regressed (not LDS disambiguation)
//  - r14: 2 independent chains in one wave -> ZERO overlap => per-MFMA
//    wave-issue occupancy (~50 cyc) is serial per wave; 8 MFMAs/step is the
//    bf16 minimum (4 row-tiles x K=64/32). Escapes would need >1 wave/SIMD
//    (chunk-matrix path: failed twice on unverifiable B-column layout,
//    r12/r13) or fp8 K=128 (same unverified-layout risk class).
__global__ __launch_bounds__(64, 1) void crf_forward_mfma(
    const float* __restrict__ feats,        // (B,T,K)
    const float* __restrict__ transitions,  // (K,K), trans[i,j] = score j->i
    const int* __restrict__ lengths,        // (B,)
    float* __restrict__ fwd_out)            // (B,)
{
    const int b   = blockIdx.x;
    const int l   = threadIdx.x;
    const int row = l & 15;   // A row / D col
    const int g   = l >> 4;   // k-group

    // fr banks: fr(t) in natural layout (lane = tag), double-buffered.
    __shared__ __align__(16) float frl[2][Kk];

    // A fragments: A[i][c] slot r = exp(trans[16i+row][tau(c,r)])
    bf16x8 A00, A01, A10, A11, A20, A21, A30, A31, S0, S1;
#define MKA(Av, i, c) {                                                       \
    const float* p = transitions + (16*(i)+row)*Kk + 32*(c) + 4*g;            \
    float4 lo = *(const float4*)p; float4 hi = *(const float4*)(p + 16);      \
    Av[0]=f2bf(__expf(lo.x)); Av[1]=f2bf(__expf(lo.y));                       \
    Av[2]=f2bf(__expf(lo.z)); Av[3]=f2bf(__expf(lo.w));                       \
    Av[4]=f2bf(__expf(hi.x)); Av[5]=f2bf(__expf(hi.y));                       \
    Av[6]=f2bf(__expf(hi.z)); Av[7]=f2bf(__expf(hi.w)); }
    MKA(A00,0,0) MKA(A01,0,1) MKA(A10,1,0) MKA(A11,1,1)
    MKA(A20,2,0) MKA(A21,2,1) MKA(A30,3,0) MKA(A31,3,1)
#undef MKA
    // Terminal fragments: row 0 = exp(trans[STOP][tau]), rows 1..15 = 0
#define MKS(Av, c) {                                                          \
    const float* p = transitions + STOP_TAG*Kk + 32*(c) + 4*g;                \
    float4 lo = *(const float4*)p; float4 hi = *(const float4*)(p + 16);      \
    const bool z = (row == 0);                                                \
    Av[0]=z?f2bf(__expf(lo.x)):(short)0; Av[1]=z?f2bf(__expf(lo.y)):(short)0; \
    Av[2]=z?f2bf(__expf(lo.z)):(short)0; Av[3]=z?f2bf(__expf(lo.w)):(short)0; \
    Av[4]=z?f2bf(__expf(hi.x)):(short)0; Av[5]=z?f2bf(__expf(hi.y)):(short)0; \
    Av[6]=z?f2bf(__expf(hi.z)):(short)0; Av[7]=z?f2bf(__expf(hi.w)):(short)0; }
    MKS(S0,0) MKS(S1,1)
#undef MKS

    const int len = lengths[b];
    const float* fb = feats + (size_t)b * Tt * Kk + l;  // natural: lane = tag

    // alpha0: 1 at START=62 -> B1 slot 6, g=3
    bf16x8 B0 = {}; bf16x8 B1 = {};
    if (g == 3) B1[6] = (short)0x3F80;  // bf16(1.0)

    const float* bank0 = &frl[0][4 * g];
    const float* bank1 = &frl[1][4 * g];

    // ---- prologue ----
    const float fr0_ = __builtin_amdgcn_exp2f(fb[0]      * LOG2E);
    const float fr1_ = __builtin_amdgcn_exp2f(fb[Kk]     * LOG2E);
    const float fr2_ = __builtin_amdgcn_exp2f(fb[2 * Kk] * LOG2E);
    const float fr3_ = __builtin_amdgcn_exp2f(fb[3 * Kk] * LOG2E);
    f32x4 FA0, FA1, FA2, FA3, FB0, FB1, FB2, FB3;
    frl[0][l] = fr0_;
    frl[1][l] = fr1_;
    __builtin_amdgcn_wave_barrier();
    FA0 = *(const f32x4*)(bank0);      FA1 = *(const f32x4*)(bank0 + 16);
    FA2 = *(const f32x4*)(bank0 + 32); FA3 = *(const f32x4*)(bank0 + 48);
    FB0 = *(const f32x4*)(bank1);      FB1 = *(const f32x4*)(bank1 + 16);
    FB2 = *(const f32x4*)(bank1 + 32); FB3 = *(const f32x4*)(bank1 + 48);
    __builtin_amdgcn_wave_barrier();
    frl[0][l] = fr2_;   // after FA/FB reads (same-wave DS FIFO)
    frl[1][l] = fr3_;
    __builtin_amdgcn_wave_barrier();

    // emit ring, 4 deep: er0..er3 = rows t+4..t+7 (rows always allocated;
    // er0 consumed 2 backedges after its load -> ~500 cyc of cover)
    float er0 = fb[4 * Kk], er1 = fb[5 * Kk], er2 = fb[6 * Kk], er3 = fb[7 * Kk];

    const f32x4 zz = {0.f, 0.f, 0.f, 0.f};
    int ktot = 0;
    int kq0 = 0, kq1 = 0, kemb = 0;  // k embedded in fr(2j), fr(2j+2), next write
    float probeA, probeB;

#define MFMA16(Aa, Bx, Cc) __builtin_amdgcn_mfma_f32_16x16x32_bf16(Aa, Bx, Cc, 0, 0, 0)

#define STEP(F0_, F1_, F2_, F3_, PR) {                                        \
    f32x4 d0 = MFMA16(A00, B0, zz); d0 = MFMA16(A01, B1, d0);                 \
    f32x4 d1 = MFMA16(A10, B0, zz); d1 = MFMA16(A11, B1, d1);                 \
    f32x4 d2 = MFMA16(A20, B0, zz); d2 = MFMA16(A21, B1, d2);                 \
    f32x4 d3 = MFMA16(A30, B0, zz); d3 = MFMA16(A31, B1, d3);                 \
    f32x4 m0 = d0 * F0_, m1 = d1 * F1_, m2 = d2 * F2_, m3 = d3 * F3_;         \
    PR = m0[0];                                                               \
    union { unsigned u[4]; bf16x8 v; } nb0, nb1;                              \
    nb0.u[0] = cvtpk(m0[0], m0[1]); nb0.u[1] = cvtpk(m0[2], m0[3]);           \
    nb0.u[2] = cvtpk(m1[0], m1[1]); nb0.u[3] = cvtpk(m1[2], m1[3]);           \
    nb1.u[0] = cvtpk(m2[0], m2[1]); nb1.u[1] = cvtpk(m2[2], m2[3]);           \
    nb1.u[2] = cvtpk(m3[0], m3[1]); nb1.u[3] = cvtpk(m3[2], m3[3]);           \
    B0 = nb0.v; B1 = nb1.v; }

    int t = 0;
    for (; t + 1 < len; t += 2) {
        // Next iteration's F (bank0 = fr(t+2), bank1 = fr(t+3)) + write data.
        f32x4 NA0 = *(const f32x4*)(bank0);      f32x4 NA1 = *(const f32x4*)(bank0 + 16);
        f32x4 NA2 = *(const f32x4*)(bank0 + 32); f32x4 NA3 = *(const f32x4*)(bank0 + 48);
        f32x4 NB0 = *(const f32x4*)(bank1);      f32x4 NB1 = *(const f32x4*)(bank1 + 16);
        f32x4 NB2 = *(const f32x4*)(bank1 + 32); f32x4 NB3 = *(const f32x4*)(bank1 + 48);
        const float frA = __builtin_amdgcn_exp2f(fmaf(er0, LOG2E, -(float)kemb));
        const float frB = __builtin_amdgcn_exp2f(er1 * LOG2E);

        STEP(FA0, FA1, FA2, FA3, probeA)
        STEP(FB0, FB1, FB2, FB3, probeB)

        __builtin_amdgcn_wave_barrier();   // all DS reads above precede writes
        frl[0][l] = frA;                   // fr(t+4), embeds kemb
        frl[1][l] = frB;                   // fr(t+5)

        // ---- bookkeeping (off the MFMA chain) ----
        ktot += kq0;
        const unsigned pb =
            (unsigned)__builtin_amdgcn_readfirstlane(__float_as_int(probeB));
        int knew = ((int)((pb >> 23) & 255) - 127) - kq1 - kemb;  // minus in-flight
        knew = (knew > 100) ? 100 : ((knew < -100) ? -100 : knew);
        kq0 = kq1; kq1 = kemb; kemb = knew;
        FA0 = NA0; FA1 = NA1; FA2 = NA2; FA3 = NA3;   // register renames
        FB0 = NB0; FB1 = NB1; FB2 = NB2; FB3 = NB3;
        er0 = er2; er1 = er3;
        const int r0 = (t + 8 < Tt) ? t + 8 : Tt - 1;
        const int r1 = (t + 9 < Tt) ? t + 9 : Tt - 1;
        er2 = fb[r0 * Kk]; er3 = fb[r1 * Kk];
        (void)probeA;
    }

    // tail (len odd): one step with FA = F(t)
    if (t < len) {
        STEP(FA0, FA1, FA2, FA3, probeA)
        ktot += kq0;
        (void)probeA;
    }

    // terminal: d4 row0 = etstop . alpha (current scale 2^-ktot)
    f32x4 d4 = MFMA16(S0, B0, zz); d4 = MFMA16(S1, B1, d4);
    const float term = __uint_as_float(
        (unsigned)__builtin_amdgcn_readfirstlane(__float_as_int(d4[0])));
    if (l == 0) fwd_out[b] = (float)ktot * LN2F + logf(term);
#undef STEP
#undef MFMA16
}

// Gold path score: fully parallel over t (lane-strided).
__global__ __launch_bounds__(64) void crf_gold_kernel(
    const float* __restrict__ feats,
    const float* __restrict__ transitions,
    const int* __restrict__ tags,     // (B,T)
    const int* __restrict__ lengths,  // (B,)
    float* __restrict__ gold_out)     // (B,)
{
    const int b = blockIdx.x;
    const int lane = threadIdx.x;
    const int len = lengths[b];
    const int* tb = tags + b * Tt;
    const float* fb = feats + (size_t)b * Tt * Kk;

    float acc = 0.f;
    for (int t = lane; t < len; t += 64) {
        const int tg = tb[t];
        const int prev = (t == 0) ? START_TAG : tb[t - 1];
        acc += transitions[tg * Kk + prev];  // score prev -> tg
        acc += fb[t * Kk + tg];              // emission
    }
    if (lane == 0) acc += transitions[STOP_TAG * Kk + tb[len - 1]];  // last -> STOP
#pragma unroll
    for (int off = 32; off >= 1; off >>= 1) acc += __shfl_xor(acc, off, 64);
    if (lane == 0) gold_out[b] = acc;
}

__global__ __launch_bounds__(512) void crf_reduce_kernel(
    const float* __restrict__ fwd, const float* __restrict__ gold,
    float* __restrict__ out)
{
    const int i = threadIdx.x;  // 0..511
    float v = fwd[i] - gold[i];
#pragma unroll
    for (int off = 32; off >= 1; off >>= 1) v += __shfl_xor(v, off, 64);
    __shared__ float ws[8];
    if ((i & 63) == 0) ws[i >> 6] = v;
    __syncthreads();
    if (i < 8) {
        float s = ws[i];
#pragma unroll
        for (int off = 4; off >= 1; off >>= 1) s += __shfl_xor(s, off, 8);
        if (i == 0) out[0] = s * (1.0f / (float)Bb);
    }
}

extern "C" void kernel_launch(void* const* d_in, const int* in_sizes, int n_in,
                              void* d_out, int out_size, void* d_ws, size_t ws_size,
                              hipStream_t stream) {
    const float* feats = (const float*)d_in[0];
    const float* trans = (const float*)d_in[1];
    const int* tags = (const int*)d_in[2];
    const int* lengths = (const int*)d_in[3];
    float* out = (float*)d_out;
    float* fwd = (float*)d_ws;
    float* gold = fwd + Bb;

    crf_gold_kernel<<<Bb, 64, 0, stream>>>(feats, trans, tags, lengths, gold);
    crf_forward_mfma<<<Bb, 64, 0, stream>>>(feats, trans, lengths, fwd);
    crf_reduce_kernel<<<1, 512, 0, stream>>>(fwd, gold, out);
}